// Round 5
// baseline (129.733 us; speedup 1.0000x reference)
//
#include <hip/hip_runtime.h>

typedef unsigned short u16;
typedef unsigned int u32;
typedef __attribute__((ext_vector_type(8))) short short8;
typedef __attribute__((ext_vector_type(4))) float f32x4;

__device__ __forceinline__ u16 f2bf(float f) {
    unsigned u = __float_as_uint(f);
    return (u16)((u + 0x7FFFu + ((u >> 16) & 1u)) >> 16);  // RNE
}
__device__ __forceinline__ u32 pack2(float a, float b) {
    return ((u32)f2bf(b) << 16) | (u32)f2bf(a);
}

// ---- DPP row-rotate helpers (16-lane rows) ----
#define ROR1 0x121
#define ROR2 0x122
#define ROR4 0x124
#define ROR8 0x128
template<int C> __device__ __forceinline__ float dppf(float x) {
    int i = __float_as_int(x);
    return __int_as_float(__builtin_amdgcn_update_dpp(i, i, C, 0xF, 0xF, false));
}
template<int C> __device__ __forceinline__ int dppi(int x) {
    return __builtin_amdgcn_update_dpp(x, x, C, 0xF, 0xF, false);
}

// ---------------------------------------------------------------------------
// L1: fused build-X + GEMM + bias + leaky + bf16 out.  grid 128 x 256.
// K=256 (2 chunks serial).  X[r][e] = emb[2*(r&3)+(e>=128)][r>>2][e&127].
// ---------------------------------------------------------------------------
__global__ __launch_bounds__(256) void k_l1(
    const float* __restrict__ emb,   // [8][16][128]
    const float* __restrict__ W,     // [256][4096]
    const float* __restrict__ bias,  // [4096]
    u16* __restrict__ H)             // [64][4096] bf16
{
    __shared__ __align__(16) u16 Alds[64][136];
    __shared__ __align__(16) u16 Wlds[32][136];
    int tid = threadIdx.x;
    int wv = tid >> 6, lane = tid & 63, c = lane & 15, g = lane >> 4;
    int c0 = blockIdx.x * 32;
    int cb = wv * 8;
    f32x4 acc0 = {0.f,0.f,0.f,0.f}, acc1 = {0.f,0.f,0.f,0.f};

    for (int ch = 0; ch < 2; ++ch) {
        {   // build+stage A[64][128]
            int row = tid >> 2, seg = tid & 3;
            int b = 2 * (row & 3) + ch, nd = row >> 2;
            const float4* src = (const float4*)(emb + (b * 16 + nd) * 128 + seg * 32);
            u32* dst = (u32*)&Alds[row][seg * 32];
            #pragma unroll
            for (int q = 0; q < 8; ++q) {
                float4 f = src[q];
                dst[2 * q]     = pack2(f.x, f.y);
                dst[2 * q + 1] = pack2(f.z, f.w);
            }
        }
        {   // stage W chunk transposed bf16: [col][k]
            const float* s0 = W + (size_t)(ch * 128 + 2 * lane) * 4096 + c0 + cb;
            float4 p0 = ((const float4*)s0)[0], p1 = ((const float4*)s0)[1];
            const float* s1 = s0 + 4096;
            float4 p2 = ((const float4*)s1)[0], p3 = ((const float4*)s1)[1];
            u32* wb = (u32*)&Wlds[0][0];
            wb[(cb + 0) * 68 + lane] = pack2(p0.x, p2.x);
            wb[(cb + 1) * 68 + lane] = pack2(p0.y, p2.y);
            wb[(cb + 2) * 68 + lane] = pack2(p0.z, p2.z);
            wb[(cb + 3) * 68 + lane] = pack2(p0.w, p2.w);
            wb[(cb + 4) * 68 + lane] = pack2(p1.x, p3.x);
            wb[(cb + 5) * 68 + lane] = pack2(p1.y, p3.y);
            wb[(cb + 6) * 68 + lane] = pack2(p1.z, p3.z);
            wb[(cb + 7) * 68 + lane] = pack2(p1.w, p3.w);
        }
        __syncthreads();
        #pragma unroll
        for (int ks = 0; ks < 4; ++ks) {
            int kk = ks * 32 + g * 8;
            short8 a8 = *(const short8*)&Alds[wv * 16 + c][kk];
            short8 b0 = *(const short8*)&Wlds[c][kk];
            short8 b1 = *(const short8*)&Wlds[16 + c][kk];
            acc0 = __builtin_amdgcn_mfma_f32_16x16x32_bf16(a8, b0, acc0, 0, 0, 0);
            acc1 = __builtin_amdgcn_mfma_f32_16x16x32_bf16(a8, b1, acc1, 0, 0, 0);
        }
        __syncthreads();
    }
    int rbase = wv * 16 + g * 4;
    #pragma unroll
    for (int rr = 0; rr < 4; ++rr) {
        int col0 = c0 + c, col1 = c0 + 16 + c;
        float v0 = acc0[rr] + bias[col0]; v0 = (v0 >= 0.f) ? v0 : 0.01f * v0;
        float v1 = acc1[rr] + bias[col1]; v1 = (v1 >= 0.f) ? v1 : 0.01f * v1;
        H[(size_t)(rbase + rr) * 4096 + col0] = f2bf(v0);
        H[(size_t)(rbase + rr) * 4096 + col1] = f2bf(v1);
    }
}

// ---------------------------------------------------------------------------
// Mid/L4 GEMM: full-K in one block.  grid (N/32) x 1024 threads.
// 16 waves = 4 k-groups (kg) x 4 row-groups.  kg owns its own LDS stage
// buffers and processes chunks ch = it*4+kg with 1-chunk prefetch.
// Final: 24KB LDS merge of the 4 kg accumulators, fused epilogue.
// MODE 0: bias+leaky -> bf16 H.   MODE 1: bias+leaky+sigmoid -> fp32 P.
// K=4096 fixed (32 chunks of 128).  No split-K partials, no atomics.
// ---------------------------------------------------------------------------
template<int MODE>
__global__ __launch_bounds__(1024) void k_mid(
    const u16* __restrict__ A,      // [64][4096] bf16
    const float* __restrict__ W,    // [4096][N] fp32
    const float* __restrict__ bias, // [N]
    u16* __restrict__ Hb,           // MODE 0 out
    float* __restrict__ Pf,         // MODE 1 out
    int N)
{
    __shared__ __align__(16) u16 Alds[4][64][136];   // 69632 B
    __shared__ __align__(16) u16 Wlds[4][32][136];   // 34816 B (total 104448)
    int tid = threadIdx.x;
    int kg = tid >> 8;
    int t  = tid & 255;
    int wv = t >> 6, lane = t & 63, c = lane & 15, g = lane >> 4;
    int c0 = blockIdx.x * 32;
    int arow = t >> 2, aseg = t & 3;
    int cb = wv * 8;
    f32x4 acc0 = {0.f,0.f,0.f,0.f}, acc1 = {0.f,0.f,0.f,0.f};

    uint4 a0, a1, a2, a3;
    float4 q0, q1, q2, q3;
    {   // prologue: chunk kg
        const uint4* as = (const uint4*)(A + ((size_t)arow << 12) + kg * 128 + aseg * 32);
        a0 = as[0]; a1 = as[1]; a2 = as[2]; a3 = as[3];
        const float* s0 = W + (size_t)(kg * 128 + 2 * lane) * N + c0 + cb;
        q0 = ((const float4*)s0)[0]; q1 = ((const float4*)s0)[1];
        const float* s1 = s0 + N;
        q2 = ((const float4*)s1)[0]; q3 = ((const float4*)s1)[1];
    }
    for (int it = 0; it < 8; ++it) {
        {   // ds_write staged regs into this kg's buffers
            uint4* ad = (uint4*)&Alds[kg][arow][aseg * 32];
            ad[0] = a0; ad[1] = a1; ad[2] = a2; ad[3] = a3;
            u32* wb = (u32*)&Wlds[kg][0][0];
            wb[(cb + 0) * 68 + lane] = pack2(q0.x, q2.x);
            wb[(cb + 1) * 68 + lane] = pack2(q0.y, q2.y);
            wb[(cb + 2) * 68 + lane] = pack2(q0.z, q2.z);
            wb[(cb + 3) * 68 + lane] = pack2(q0.w, q2.w);
            wb[(cb + 4) * 68 + lane] = pack2(q1.x, q3.x);
            wb[(cb + 5) * 68 + lane] = pack2(q1.y, q3.y);
            wb[(cb + 6) * 68 + lane] = pack2(q1.z, q3.z);
            wb[(cb + 7) * 68 + lane] = pack2(q1.w, q3.w);
        }
        __syncthreads();
        if (it < 7) {   // prefetch chunk (it+1)*4+kg; overlaps MFMA below
            int ch = (it + 1) * 4 + kg;
            const uint4* as = (const uint4*)(A + ((size_t)arow << 12) + ch * 128 + aseg * 32);
            a0 = as[0]; a1 = as[1]; a2 = as[2]; a3 = as[3];
            const float* s0 = W + (size_t)(ch * 128 + 2 * lane) * N + c0 + cb;
            q0 = ((const float4*)s0)[0]; q1 = ((const float4*)s0)[1];
            const float* s1 = s0 + N;
            q2 = ((const float4*)s1)[0]; q3 = ((const float4*)s1)[1];
        }
        #pragma unroll
        for (int ks = 0; ks < 4; ++ks) {
            int kk = ks * 32 + g * 8;
            short8 a8 = *(const short8*)&Alds[kg][wv * 16 + c][kk];
            short8 b0 = *(const short8*)&Wlds[kg][c][kk];
            short8 b1 = *(const short8*)&Wlds[kg][16 + c][kk];
            acc0 = __builtin_amdgcn_mfma_f32_16x16x32_bf16(a8, b0, acc0, 0, 0, 0);
            acc1 = __builtin_amdgcn_mfma_f32_16x16x32_bf16(a8, b1, acc1, 0, 0, 0);
        }
        __syncthreads();
    }

    // merge 4 kg accumulators via LDS (reuse Alds area; all staging done)
    float* scr = (float*)&Alds[0][0][0];   // 6144 floats = 24 KB
    if (kg > 0) {
        float4* s4 = (float4*)&scr[((kg - 1) * 256 + t) * 8];
        s4[0] = *(float4*)&acc0;
        s4[1] = *(float4*)&acc1;
    }
    __syncthreads();
    if (kg == 0) {
        #pragma unroll
        for (int q = 0; q < 3; ++q) {
            const float4* s4 = (const float4*)&scr[(q * 256 + t) * 8];
            float4 p0 = s4[0], p1 = s4[1];
            acc0[0] += p0.x; acc0[1] += p0.y; acc0[2] += p0.z; acc0[3] += p0.w;
            acc1[0] += p1.x; acc1[1] += p1.y; acc1[2] += p1.z; acc1[3] += p1.w;
        }
        int rbase = wv * 16 + g * 4;
        #pragma unroll
        for (int rr = 0; rr < 4; ++rr) {
            int col0 = c0 + c, col1 = c0 + 16 + c;
            float v0 = acc0[rr] + bias[col0];
            float v1 = acc1[rr] + bias[col1];
            v0 = (v0 >= 0.f) ? v0 : 0.01f * v0;
            v1 = (v1 >= 0.f) ? v1 : 0.01f * v1;
            if (MODE == 0) {
                Hb[(size_t)(rbase + rr) * N + col0] = f2bf(v0);
                Hb[(size_t)(rbase + rr) * N + col1] = f2bf(v1);
            } else {
                Pf[(size_t)(rbase + rr) * N + col0] = 1.0f / (1.0f + __expf(-v0));
                Pf[(size_t)(rbase + rr) * N + col1] = 1.0f / (1.0f + __expf(-v1));
            }
        }
    }
}

// ---------------------------------------------------------------------------
// 50 power iterations (VALU/DPP only) + factored output reduction.
// ---------------------------------------------------------------------------
__global__ __launch_bounds__(1024) void k_power_out(
    const float* __restrict__ pol,  // [64][16][16] fp32 (post-sigmoid)
    const float* __restrict__ Ts,   // [8][16][16]
    float* __restrict__ out)        // [8][16]
{
    __shared__ float pol_lds[16384];
    __shared__ float w_lds[64][16];
    __shared__ float Ts_lds[2048];
    __shared__ float Cmat[8][16];

    int tid = threadIdx.x;
    int m = tid >> 4, r = tid & 15;

    {   // stage all 64 matrices (64 KB) to LDS
        const float4* p4 = (const float4*)(pol + tid * 16);
        float4* q4 = (float4*)&pol_lds[tid * 16];
        q4[0] = p4[0]; q4[1] = p4[1]; q4[2] = p4[2]; q4[3] = p4[3];
    }
    Ts_lds[tid] = Ts[tid];
    Ts_lds[tid + 1024] = Ts[tid + 1024];
    __syncthreads();

    // gather row r of matrix m with DPP-rotated index (matches va rotation)
    float Mr[8], Ms[8];
    {
        int mb = m * 256 + r * 16;
        int idx = r;
        #pragma unroll
        for (int k = 0; k < 8; ++k) { Mr[k] = pol_lds[mb + idx]; idx = dppi<ROR1>(idx); }
        #pragma unroll
        for (int k = 0; k < 8; ++k) { Ms[k] = pol_lds[mb + idx]; idx = dppi<ROR1>(idx); }
    }

    float v = 1.0f;
    #pragma unroll 1
    for (int it = 0; it < 50; ++it) {
        float va = v, vb = dppf<ROR8>(v);
        float w = 0.f, w2 = 0.f;
        #pragma unroll
        for (int k = 0; k < 8; ++k) {
            w  = fmaf(Mr[k], va, w);
            w2 = fmaf(Ms[k], vb, w2);
            if (k < 7) { va = dppf<ROR1>(va); vb = dppf<ROR1>(vb); }
        }
        w += w2;
        if ((it & 7) == 7) {   // positive-sum renorm; scale cancels in output
            float s = w;
            s += dppf<ROR8>(s); s += dppf<ROR4>(s);
            s += dppf<ROR2>(s); s += dppf<ROR1>(s);
            w *= 1.0f / s;
        }
        v = w;
    }
    w_lds[m][r] = v;
    __syncthreads();

    if (tid < 128) {
        int b = tid >> 4, x = tid & 15;
        float s = 0.f;
        if (b < 4) {                             // R[b][s=x] = sum_t Ts[b][x][t]
            const float* row = &Ts_lds[(b * 16 + x) * 16];
            #pragma unroll
            for (int t = 0; t < 16; ++t) s += row[t];
        } else {                                 // C[b][t=x]
            int j = b - 4;
            #pragma unroll
            for (int si = 0; si < 16; ++si)
                s += Ts_lds[(b * 16 + si) * 16 + x] / w_lds[x * 4 + j][si];
        }
        Cmat[b][x] = s;
    }
    __syncthreads();

    if (tid < 128) {
        int b = tid >> 4, n = tid & 15;
        float o = 0.f;
        if (b < 4) {
            #pragma unroll
            for (int si = 0; si < 16; ++si) {
                const float* wr = w_lds[si * 4 + b];
                o += wr[n] / wr[si] * Cmat[b][si];
            }
        } else {
            int j = b - 4;
            #pragma unroll
            for (int t = 0; t < 16; ++t)
                o += w_lds[t * 4 + j][n] * Cmat[b][t];
        }
        out[b * 16 + n] = o;
    }
}

// ---------------------------------------------------------------------------
extern "C" void kernel_launch(void* const* d_in, const int* in_sizes, int n_in,
                              void* d_out, int out_size, void* d_ws, size_t ws_size,
                              hipStream_t stream)
{
    const float* emb = (const float*)d_in[0];
    const float* Ts  = (const float*)d_in[2];
    const float* W1  = (const float*)d_in[3];  const float* b1 = (const float*)d_in[4];
    const float* W2  = (const float*)d_in[5];  const float* b2 = (const float*)d_in[6];
    const float* W3  = (const float*)d_in[7];  const float* b3 = (const float*)d_in[8];
    const float* W4  = (const float*)d_in[9];  const float* b4 = (const float*)d_in[10];
    float* outp = (float*)d_out;

    char* ws = (char*)d_ws;
    u16*   Ha  = (u16*)(ws + 0);            // 512 KB  [64][4096] bf16
    u16*   Hb  = (u16*)(ws + 524288);       // 512 KB  [64][4096] bf16
    float* pol = (float*)(ws + 1048576);    //  64 KB  [64][16][16] fp32

    k_l1      <<<128, 256,  0, stream>>>(emb, W1, b1, Ha);
    k_mid<0>  <<<128, 1024, 0, stream>>>(Ha, W2, b2, Hb, nullptr, 4096);
    k_mid<0>  <<<128, 1024, 0, stream>>>(Hb, W3, b3, Ha, nullptr, 4096);
    k_mid<1>  <<<8,   1024, 0, stream>>>(Ha, W4, b4, nullptr, pol, 256);
    k_power_out<<<1,  1024, 0, stream>>>(pol, Ts, outp);

    (void)in_sizes; (void)n_in; (void)out_size; (void)ws_size;
}

// Round 6
// 85.791 us; speedup vs baseline: 1.5122x; 1.5122x over previous
//
#include <hip/hip_runtime.h>

typedef unsigned short u16;
typedef unsigned int u32;
typedef __attribute__((ext_vector_type(8))) short short8;
typedef __attribute__((ext_vector_type(4))) float f32x4;

__device__ __forceinline__ u16 f2bf(float f) {
    unsigned u = __float_as_uint(f);
    return (u16)((u + 0x7FFFu + ((u >> 16) & 1u)) >> 16);  // RNE
}
__device__ __forceinline__ u32 pack2(float a, float b) {
    return ((u32)f2bf(b) << 16) | (u32)f2bf(a);
}

// ---- DPP row-rotate helpers (16-lane rows) ----
#define ROR1 0x121
#define ROR2 0x122
#define ROR4 0x124
#define ROR8 0x128
template<int C> __device__ __forceinline__ float dppf(float x) {
    int i = __float_as_int(x);
    return __int_as_float(__builtin_amdgcn_update_dpp(i, i, C, 0xF, 0xF, false));
}
template<int C> __device__ __forceinline__ int dppi(int x) {
    return __builtin_amdgcn_update_dpp(x, x, C, 0xF, 0xF, false);
}

// ---------------------------------------------------------------------------
// Unified GEMM: C[64][c0..c0+128) over k-slice [k0, k0+kchunk).
// grid (N/128, KS), 256 threads, __launch_bounds__(256,1) to keep prefetch
// registers live.  W read pattern: threads 0..15 cover one full 512B row
// segment (32B each, 2 adjacent rows/thread) -> canonical coalescing.
// W LDS k-major [kp][132] u32 (k-pairs packed bf16); A row-major [64][40].
// SRC 0: A from global bf16 [64][4096].  SRC 1: build X from emb (reshape
//        quirk: X[r][e] = emb[2*(r&3)+(e>=128)][r>>2][e&127]).
// EPI 0: write fp32 partial slice Cp[by].  EPI 1: bias+leaky -> bf16 Ho.
// EPI 2: bias+leaky+sigmoid -> fp32 Po.
// ---------------------------------------------------------------------------
template<int SRC, int EPI>
__global__ __launch_bounds__(256, 1) void k_gemm(
    const u16* __restrict__ A, const float* __restrict__ emb,
    const float* __restrict__ W, const float* __restrict__ bias,
    float* __restrict__ Cp, u16* __restrict__ Ho, float* __restrict__ Po,
    int N, int kchunk)
{
    __shared__ __align__(16) u16 Alds[64][40];     // 5120 B
    __shared__ __align__(16) u32 Wlds[16 * 132];   // 8448 B
    int tid = threadIdx.x;
    int wv = tid >> 6, lane = tid & 63, c = lane & 15, g = lane >> 4;
    int c0 = blockIdx.x * 128;
    int k0 = blockIdx.y * kchunk;
    int nit = kchunk >> 5;

    int ar = tid >> 2, aseg = tid & 3;          // A staging: row, 8-elem seg
    int kp = tid >> 4, cbase = (tid & 15) * 8;  // W staging: k-pair, col base

    f32x4 acc[8];
    #pragma unroll
    for (int n = 0; n < 8; ++n) acc[n] = (f32x4){0.f, 0.f, 0.f, 0.f};

    uint4 av;
    float4 q0, q1, q2, q3;

    // ---- prologue: chunk 0 loads
    {
        if (SRC == 0) {
            av = *(const uint4*)(A + (size_t)ar * 4096 + k0 + aseg * 8);
        } else {
            int e0 = aseg * 8;
            int b = 2 * (ar & 3) + (e0 >> 7), d = e0 & 127;
            const float4* s = (const float4*)(emb + (b * 16 + (ar >> 2)) * 128 + d);
            float4 f0 = s[0], f1 = s[1];
            av.x = pack2(f0.x, f0.y); av.y = pack2(f0.z, f0.w);
            av.z = pack2(f1.x, f1.y); av.w = pack2(f1.z, f1.w);
        }
        const float* s0 = W + (size_t)(k0 + 2 * kp) * N + c0 + cbase;
        q0 = ((const float4*)s0)[0]; q1 = ((const float4*)s0)[1];
        const float* s1 = s0 + N;
        q2 = ((const float4*)s1)[0]; q3 = ((const float4*)s1)[1];
    }

    for (int it = 0; it < nit; ++it) {
        // ---- ds_write staged regs
        *(uint4*)&Alds[ar][aseg * 8] = av;
        {
            uint4 w0, w1;
            w0.x = pack2(q0.x, q2.x); w0.y = pack2(q0.y, q2.y);
            w0.z = pack2(q0.z, q2.z); w0.w = pack2(q0.w, q2.w);
            w1.x = pack2(q1.x, q3.x); w1.y = pack2(q1.y, q3.y);
            w1.z = pack2(q1.z, q3.z); w1.w = pack2(q1.w, q3.w);
            uint4* wd = (uint4*)&Wlds[kp * 132 + cbase];
            wd[0] = w0; wd[1] = w1;
        }
        __syncthreads();

        if (it + 1 < nit) {   // prefetch chunk it+1 (batch-issued, 1-deep)
            int kc = (it + 1) * 32;
            if (SRC == 0) {
                av = *(const uint4*)(A + (size_t)ar * 4096 + k0 + kc + aseg * 8);
            } else {
                int e0 = kc + aseg * 8;
                int b = 2 * (ar & 3) + (e0 >> 7), d = e0 & 127;
                const float4* s = (const float4*)(emb + (b * 16 + (ar >> 2)) * 128 + d);
                float4 f0 = s[0], f1 = s[1];
                av.x = pack2(f0.x, f0.y); av.y = pack2(f0.z, f0.w);
                av.z = pack2(f1.x, f1.y); av.w = pack2(f1.z, f1.w);
            }
            const float* s0 = W + (size_t)(k0 + kc + 2 * kp) * N + c0 + cbase;
            q0 = ((const float4*)s0)[0]; q1 = ((const float4*)s0)[1];
            const float* s1 = s0 + N;
            q2 = ((const float4*)s1)[0]; q3 = ((const float4*)s1)[1];
        }

        // ---- frags + MFMA (k-slot convention: slot = g*8+i for A and B)
        short8 a8 = *(const short8*)&Alds[wv * 16 + c][g * 8];
        #pragma unroll
        for (int n = 0; n < 8; ++n) {
            int base = n * 16 + c;
            union { u32 u[4]; short8 s; } bb;
            bb.u[0] = Wlds[(g * 4 + 0) * 132 + base];
            bb.u[1] = Wlds[(g * 4 + 1) * 132 + base];
            bb.u[2] = Wlds[(g * 4 + 2) * 132 + base];
            bb.u[3] = Wlds[(g * 4 + 3) * 132 + base];
            acc[n] = __builtin_amdgcn_mfma_f32_16x16x32_bf16(a8, bb.s, acc[n], 0, 0, 0);
        }
        __syncthreads();
    }

    // ---- epilogue (D layout: col = lane&15, row = g*4+rr)
    #pragma unroll
    for (int n = 0; n < 8; ++n) {
        #pragma unroll
        for (int rr = 0; rr < 4; ++rr) {
            int grow = wv * 16 + g * 4 + rr;
            int gcol = c0 + n * 16 + c;
            float v = acc[n][rr];
            if (EPI == 0) {
                Cp[(size_t)blockIdx.y * 64 * N + (size_t)grow * N + gcol] = v;
            } else {
                v += bias[gcol];
                v = (v >= 0.f) ? v : 0.01f * v;
                if (EPI == 1) Ho[(size_t)grow * N + gcol] = f2bf(v);
                else          Po[(size_t)grow * N + gcol] = 1.0f / (1.0f + __expf(-v));
            }
        }
    }
}

// ---------------------------------------------------------------------------
// Reduce split-K partials + bias + leaky; mode 0 -> bf16 H, mode 1 ->
// sigmoid(leaky) fp32.  grid = 64*N/256.
// ---------------------------------------------------------------------------
__global__ void k_reduce(const float* __restrict__ Cp, const float* __restrict__ bias,
                         u16* __restrict__ Hb, float* __restrict__ Pf,
                         int N, int ksplit, int mode)
{
    int idx = blockIdx.x * 256 + threadIdx.x;
    int col = idx & (N - 1);
    float s = bias[col];
    for (int k = 0; k < ksplit; ++k) s += Cp[(size_t)k * 64 * N + idx];
    float a = (s >= 0.f) ? s : 0.01f * s;
    if (mode == 0) Hb[idx] = f2bf(a);
    else           Pf[idx] = 1.0f / (1.0f + __expf(-a));
}

// ---------------------------------------------------------------------------
// 50 power iterations (VALU/DPP only) + factored output reduction.
// ---------------------------------------------------------------------------
__global__ __launch_bounds__(1024) void k_power_out(
    const float* __restrict__ pol,  // [64][16][16] fp32 (post-sigmoid)
    const float* __restrict__ Ts,   // [8][16][16]
    float* __restrict__ out)        // [8][16]
{
    __shared__ float pol_lds[16384];
    __shared__ float w_lds[64][16];
    __shared__ float Ts_lds[2048];
    __shared__ float Cmat[8][16];

    int tid = threadIdx.x;
    int m = tid >> 4, r = tid & 15;

    {   // stage all 64 matrices (64 KB) to LDS
        const float4* p4 = (const float4*)(pol + tid * 16);
        float4* q4 = (float4*)&pol_lds[tid * 16];
        q4[0] = p4[0]; q4[1] = p4[1]; q4[2] = p4[2]; q4[3] = p4[3];
    }
    Ts_lds[tid] = Ts[tid];
    Ts_lds[tid + 1024] = Ts[tid + 1024];
    __syncthreads();

    // gather row r of matrix m with DPP-rotated index (matches va rotation)
    float Mr[8], Ms[8];
    {
        int mb = m * 256 + r * 16;
        int idx = r;
        #pragma unroll
        for (int k = 0; k < 8; ++k) { Mr[k] = pol_lds[mb + idx]; idx = dppi<ROR1>(idx); }
        #pragma unroll
        for (int k = 0; k < 8; ++k) { Ms[k] = pol_lds[mb + idx]; idx = dppi<ROR1>(idx); }
    }

    float v = 1.0f;
    #pragma unroll 1
    for (int it = 0; it < 50; ++it) {
        float va = v, vb = dppf<ROR8>(v);
        float w = 0.f, w2 = 0.f;
        #pragma unroll
        for (int k = 0; k < 8; ++k) {
            w  = fmaf(Mr[k], va, w);
            w2 = fmaf(Ms[k], vb, w2);
            if (k < 7) { va = dppf<ROR1>(va); vb = dppf<ROR1>(vb); }
        }
        w += w2;
        if ((it & 7) == 7) {   // positive-sum renorm; scale cancels in output
            float s = w;
            s += dppf<ROR8>(s); s += dppf<ROR4>(s);
            s += dppf<ROR2>(s); s += dppf<ROR1>(s);
            w *= 1.0f / s;
        }
        v = w;
    }
    w_lds[m][r] = v;
    __syncthreads();

    if (tid < 128) {
        int b = tid >> 4, x = tid & 15;
        float s = 0.f;
        if (b < 4) {                             // R[b][s=x] = sum_t Ts[b][x][t]
            const float* row = &Ts_lds[(b * 16 + x) * 16];
            #pragma unroll
            for (int t = 0; t < 16; ++t) s += row[t];
        } else {                                 // C[b][t=x]
            int j = b - 4;
            #pragma unroll
            for (int si = 0; si < 16; ++si)
                s += Ts_lds[(b * 16 + si) * 16 + x] / w_lds[x * 4 + j][si];
        }
        Cmat[b][x] = s;
    }
    __syncthreads();

    if (tid < 128) {
        int b = tid >> 4, n = tid & 15;
        float o = 0.f;
        if (b < 4) {
            #pragma unroll
            for (int si = 0; si < 16; ++si) {
                const float* wr = w_lds[si * 4 + b];
                o += wr[n] / wr[si] * Cmat[b][si];
            }
        } else {
            int j = b - 4;
            #pragma unroll
            for (int t = 0; t < 16; ++t)
                o += w_lds[t * 4 + j][n] * Cmat[b][t];
        }
        out[b * 16 + n] = o;
    }
}

// ---------------------------------------------------------------------------
extern "C" void kernel_launch(void* const* d_in, const int* in_sizes, int n_in,
                              void* d_out, int out_size, void* d_ws, size_t ws_size,
                              hipStream_t stream)
{
    const float* emb = (const float*)d_in[0];
    const float* Ts  = (const float*)d_in[2];
    const float* W1  = (const float*)d_in[3];  const float* b1 = (const float*)d_in[4];
    const float* W2  = (const float*)d_in[5];  const float* b2 = (const float*)d_in[6];
    const float* W3  = (const float*)d_in[7];  const float* b3 = (const float*)d_in[8];
    const float* W4  = (const float*)d_in[9];  const float* b4 = (const float*)d_in[10];
    float* outp = (float*)d_out;

    char* ws = (char*)d_ws;
    u16*   Ha  = (u16*)(ws + 0);            // 512 KB  [64][4096] bf16
    u16*   Hb  = (u16*)(ws + 524288);       // 512 KB  [64][4096] bf16
    float* pol = (float*)(ws + 1048576);    //  64 KB  [64][16][16] fp32
    float* Cp  = (float*)(ws + 1114112);    //   8 MB  split-K partials

    // L1: fused build-X + GEMM + epilogue -> Ha   (K=256, full-K, 32 blocks)
    k_gemm<1, 1><<<dim3(32, 1), 256, 0, stream>>>(
        nullptr, emb, W1, b1, nullptr, Ha, nullptr, 4096, 256);

    // L2: split-K KS=8 -> Cp; reduce -> Hb
    k_gemm<0, 0><<<dim3(32, 8), 256, 0, stream>>>(
        Ha, nullptr, W2, nullptr, Cp, nullptr, nullptr, 4096, 512);
    k_reduce<<<1024, 256, 0, stream>>>(Cp, b2, Hb, nullptr, 4096, 8, 0);

    // L3: split-K KS=8 -> Cp; reduce -> Ha
    k_gemm<0, 0><<<dim3(32, 8), 256, 0, stream>>>(
        Hb, nullptr, W3, nullptr, Cp, nullptr, nullptr, 4096, 512);
    k_reduce<<<1024, 256, 0, stream>>>(Cp, b3, Ha, nullptr, 4096, 8, 0);

    // L4: N=256, split-K KS=32 -> Cp; reduce(+sigmoid) -> pol
    k_gemm<0, 0><<<dim3(2, 32), 256, 0, stream>>>(
        Ha, nullptr, W4, nullptr, Cp, nullptr, nullptr, 256, 128);
    k_reduce<<<64, 256, 0, stream>>>(Cp, b4, nullptr, pol, 256, 32, 1);

    // Power iteration + factored output
    k_power_out<<<1, 1024, 0, stream>>>(pol, Ts, outp);

    (void)in_sizes; (void)n_in; (void)out_size; (void)ws_size;
}

// Round 7
// 79.624 us; speedup vs baseline: 1.6293x; 1.0775x over previous
//
#include <hip/hip_runtime.h>

typedef unsigned short u16;
typedef unsigned int u32;
typedef __attribute__((ext_vector_type(8))) short short8;
typedef __attribute__((ext_vector_type(4))) float f32x4;

__device__ __forceinline__ u16 f2bf(float f) {
    unsigned u = __float_as_uint(f);
    return (u16)((u + 0x7FFFu + ((u >> 16) & 1u)) >> 16);  // RNE
}
__device__ __forceinline__ u32 pack2(float a, float b) {
    return ((u32)f2bf(b) << 16) | (u32)f2bf(a);
}

// ---- DPP row-rotate helpers (16-lane rows) ----
#define ROR1 0x121
#define ROR2 0x122
#define ROR4 0x124
#define ROR8 0x128
template<int C> __device__ __forceinline__ float dppf(float x) {
    int i = __float_as_int(x);
    return __int_as_float(__builtin_amdgcn_update_dpp(i, i, C, 0xF, 0xF, false));
}
template<int C> __device__ __forceinline__ int dppi(int x) {
    return __builtin_amdgcn_update_dpp(x, x, C, 0xF, 0xF, false);
}

// ---------------------------------------------------------------------------
// Unified GEMM: C[64][c0..c0+128) over k-slice [k0, k0+kchunk).
// grid (N/128, KS), 256 threads.  DEPTH-2 register pipeline: two named
// prefetch sets (A/B), loop unrolled x2 so all indexing is static — loads
// issue two phases ahead of their ds_write, covering HBM latency.
// __launch_bounds__(256,2): cap VGPR at 256 so 2 blocks/CU co-reside.
// W read: threads 0..15 cover one full 512B row segment (canonical
// coalescing); W LDS k-pair-major [kp][132] u32 (packed bf16 pairs).
// SRC 0: A from global bf16 [64][4096].  SRC 1: build X from emb (reshape
//        quirk: X[r][e] = emb[2*(r&3)+(e>=128)][r>>2][e&127]).
// EPI 0: fp32 partial slice Cp[by].  EPI 1: bias+leaky -> bf16 Ho.
// EPI 2: bias+leaky+sigmoid -> fp32 Po.   nit = kchunk/32 must be EVEN.
// ---------------------------------------------------------------------------
template<int SRC, int EPI>
__global__ __launch_bounds__(256, 2) void k_gemm(
    const u16* __restrict__ A, const float* __restrict__ emb,
    const float* __restrict__ W, const float* __restrict__ bias,
    float* __restrict__ Cp, u16* __restrict__ Ho, float* __restrict__ Po,
    int N, int kchunk)
{
    __shared__ __align__(16) u16 Alds[64][40];     // 5120 B
    __shared__ __align__(16) u32 Wlds[16 * 132];   // 8448 B
    int tid = threadIdx.x;
    int wv = tid >> 6, lane = tid & 63, c = lane & 15, g = lane >> 4;
    int c0 = blockIdx.x * 128;
    int k0 = blockIdx.y * kchunk;
    int nit = kchunk >> 5;

    int ar = tid >> 2, aseg = tid & 3;          // A staging: row, 8-elem seg
    int kp = tid >> 4, cbase = (tid & 15) * 8;  // W staging: k-pair, col base

    f32x4 acc[8];
    #pragma unroll
    for (int n = 0; n < 8; ++n) acc[n] = (f32x4){0.f, 0.f, 0.f, 0.f};

    auto loadA = [&](int kc, uint4& av) {
        if (SRC == 0) {
            av = *(const uint4*)(A + (size_t)ar * 4096 + k0 + kc + aseg * 8);
        } else {
            int e0 = kc + aseg * 8;
            int b = 2 * (ar & 3) + (e0 >> 7), d = e0 & 127;
            const float4* s = (const float4*)(emb + (b * 16 + (ar >> 2)) * 128 + d);
            float4 f0 = s[0], f1 = s[1];
            av.x = pack2(f0.x, f0.y); av.y = pack2(f0.z, f0.w);
            av.z = pack2(f1.x, f1.y); av.w = pack2(f1.z, f1.w);
        }
    };
    auto loadW = [&](int kc, float4& q0, float4& q1, float4& q2, float4& q3) {
        const float* s0 = W + (size_t)(k0 + kc + 2 * kp) * N + c0 + cbase;
        q0 = ((const float4*)s0)[0]; q1 = ((const float4*)s0)[1];
        const float* s1 = s0 + N;
        q2 = ((const float4*)s1)[0]; q3 = ((const float4*)s1)[1];
    };
    auto stage = [&](const uint4& av, const float4& q0, const float4& q1,
                     const float4& q2, const float4& q3) {
        *(uint4*)&Alds[ar][aseg * 8] = av;
        uint4 w0, w1;
        w0.x = pack2(q0.x, q2.x); w0.y = pack2(q0.y, q2.y);
        w0.z = pack2(q0.z, q2.z); w0.w = pack2(q0.w, q2.w);
        w1.x = pack2(q1.x, q3.x); w1.y = pack2(q1.y, q3.y);
        w1.z = pack2(q1.z, q3.z); w1.w = pack2(q1.w, q3.w);
        uint4* wd = (uint4*)&Wlds[kp * 132 + cbase];
        wd[0] = w0; wd[1] = w1;
    };
    auto compute = [&]() {
        short8 a8 = *(const short8*)&Alds[wv * 16 + c][g * 8];
        #pragma unroll
        for (int n = 0; n < 8; ++n) {
            int base = n * 16 + c;
            union { u32 u[4]; short8 s; } bb;
            bb.u[0] = Wlds[(g * 4 + 0) * 132 + base];
            bb.u[1] = Wlds[(g * 4 + 1) * 132 + base];
            bb.u[2] = Wlds[(g * 4 + 2) * 132 + base];
            bb.u[3] = Wlds[(g * 4 + 3) * 132 + base];
            acc[n] = __builtin_amdgcn_mfma_f32_16x16x32_bf16(a8, bb.s, acc[n], 0, 0, 0);
        }
    };

    // ---- depth-2 pipeline, two named register sets (static indexing)
    uint4 avA, avB;
    float4 qA0, qA1, qA2, qA3, qB0, qB1, qB2, qB3;
    loadA(0, avA);  loadW(0, qA0, qA1, qA2, qA3);
    loadA(32, avB); loadW(32, qB0, qB1, qB2, qB3);

    for (int it = 0; it < nit; it += 2) {
        stage(avA, qA0, qA1, qA2, qA3);
        __syncthreads();
        if (it + 2 < nit) {
            loadA((it + 2) * 32, avA);
            loadW((it + 2) * 32, qA0, qA1, qA2, qA3);
        }
        compute();
        __syncthreads();

        stage(avB, qB0, qB1, qB2, qB3);
        __syncthreads();
        if (it + 3 < nit) {
            loadA((it + 3) * 32, avB);
            loadW((it + 3) * 32, qB0, qB1, qB2, qB3);
        }
        compute();
        __syncthreads();
    }

    // ---- epilogue (D layout: col = lane&15, row = g*4+rr)
    #pragma unroll
    for (int n = 0; n < 8; ++n) {
        #pragma unroll
        for (int rr = 0; rr < 4; ++rr) {
            int grow = wv * 16 + g * 4 + rr;
            int gcol = c0 + n * 16 + c;
            float v = acc[n][rr];
            if (EPI == 0) {
                Cp[(size_t)blockIdx.y * 64 * N + (size_t)grow * N + gcol] = v;
            } else {
                v += bias[gcol];
                v = (v >= 0.f) ? v : 0.01f * v;
                if (EPI == 1) Ho[(size_t)grow * N + gcol] = f2bf(v);
                else          Po[(size_t)grow * N + gcol] = 1.0f / (1.0f + __expf(-v));
            }
        }
    }
}

// ---------------------------------------------------------------------------
// Reduce split-K partials + bias + leaky; mode 0 -> bf16 H, mode 1 ->
// sigmoid(leaky) fp32.  grid = 64*N/256.
// ---------------------------------------------------------------------------
__global__ void k_reduce(const float* __restrict__ Cp, const float* __restrict__ bias,
                         u16* __restrict__ Hb, float* __restrict__ Pf,
                         int N, int ksplit, int mode)
{
    int idx = blockIdx.x * 256 + threadIdx.x;
    int col = idx & (N - 1);
    float s = bias[col];
    #pragma unroll 4
    for (int k = 0; k < ksplit; ++k) s += Cp[(size_t)k * 64 * N + idx];
    float a = (s >= 0.f) ? s : 0.01f * s;
    if (mode == 0) Hb[idx] = f2bf(a);
    else           Pf[idx] = 1.0f / (1.0f + __expf(-a));
}

// ---------------------------------------------------------------------------
// 50 power iterations (VALU/DPP only) + factored output reduction.
// ---------------------------------------------------------------------------
__global__ __launch_bounds__(1024) void k_power_out(
    const float* __restrict__ pol,  // [64][16][16] fp32 (post-sigmoid)
    const float* __restrict__ Ts,   // [8][16][16]
    float* __restrict__ out)        // [8][16]
{
    __shared__ float pol_lds[16384];
    __shared__ float w_lds[64][16];
    __shared__ float Ts_lds[2048];
    __shared__ float Cmat[8][16];

    int tid = threadIdx.x;
    int m = tid >> 4, r = tid & 15;

    {   // stage all 64 matrices (64 KB) to LDS
        const float4* p4 = (const float4*)(pol + tid * 16);
        float4* q4 = (float4*)&pol_lds[tid * 16];
        q4[0] = p4[0]; q4[1] = p4[1]; q4[2] = p4[2]; q4[3] = p4[3];
    }
    Ts_lds[tid] = Ts[tid];
    Ts_lds[tid + 1024] = Ts[tid + 1024];
    __syncthreads();

    // gather row r of matrix m with DPP-rotated index (matches va rotation)
    float Mr[8], Ms[8];
    {
        int mb = m * 256 + r * 16;
        int idx = r;
        #pragma unroll
        for (int k = 0; k < 8; ++k) { Mr[k] = pol_lds[mb + idx]; idx = dppi<ROR1>(idx); }
        #pragma unroll
        for (int k = 0; k < 8; ++k) { Ms[k] = pol_lds[mb + idx]; idx = dppi<ROR1>(idx); }
    }

    float v = 1.0f;
    #pragma unroll 1
    for (int it = 0; it < 50; ++it) {
        float va = v, vb = dppf<ROR8>(v);
        float w = 0.f, w2 = 0.f;
        #pragma unroll
        for (int k = 0; k < 8; ++k) {
            w  = fmaf(Mr[k], va, w);
            w2 = fmaf(Ms[k], vb, w2);
            if (k < 7) { va = dppf<ROR1>(va); vb = dppf<ROR1>(vb); }
        }
        w += w2;
        if ((it & 7) == 7) {   // positive-sum renorm; scale cancels in output
            float s = w;
            s += dppf<ROR8>(s); s += dppf<ROR4>(s);
            s += dppf<ROR2>(s); s += dppf<ROR1>(s);
            w *= 1.0f / s;
        }
        v = w;
    }
    w_lds[m][r] = v;
    __syncthreads();

    if (tid < 128) {
        int b = tid >> 4, x = tid & 15;
        float s = 0.f;
        if (b < 4) {                             // R[b][s=x] = sum_t Ts[b][x][t]
            const float* row = &Ts_lds[(b * 16 + x) * 16];
            #pragma unroll
            for (int t = 0; t < 16; ++t) s += row[t];
        } else {                                 // C[b][t=x]
            int j = b - 4;
            #pragma unroll
            for (int si = 0; si < 16; ++si)
                s += Ts_lds[(b * 16 + si) * 16 + x] / w_lds[x * 4 + j][si];
        }
        Cmat[b][x] = s;
    }
    __syncthreads();

    if (tid < 128) {
        int b = tid >> 4, n = tid & 15;
        float o = 0.f;
        if (b < 4) {
            #pragma unroll
            for (int si = 0; si < 16; ++si) {
                const float* wr = w_lds[si * 4 + b];
                o += wr[n] / wr[si] * Cmat[b][si];
            }
        } else {
            int j = b - 4;
            #pragma unroll
            for (int t = 0; t < 16; ++t)
                o += w_lds[t * 4 + j][n] * Cmat[b][t];
        }
        out[b * 16 + n] = o;
    }
}

// ---------------------------------------------------------------------------
extern "C" void kernel_launch(void* const* d_in, const int* in_sizes, int n_in,
                              void* d_out, int out_size, void* d_ws, size_t ws_size,
                              hipStream_t stream)
{
    const float* emb = (const float*)d_in[0];
    const float* Ts  = (const float*)d_in[2];
    const float* W1  = (const float*)d_in[3];  const float* b1 = (const float*)d_in[4];
    const float* W2  = (const float*)d_in[5];  const float* b2 = (const float*)d_in[6];
    const float* W3  = (const float*)d_in[7];  const float* b3 = (const float*)d_in[8];
    const float* W4  = (const float*)d_in[9];  const float* b4 = (const float*)d_in[10];
    float* outp = (float*)d_out;

    char* ws = (char*)d_ws;
    u16*   Ha  = (u16*)(ws + 0);            // 512 KB  [64][4096] bf16
    u16*   Hb  = (u16*)(ws + 524288);       // 512 KB  [64][4096] bf16
    float* pol = (float*)(ws + 1048576);    //  64 KB  [64][16][16] fp32
    float* Cp  = (float*)(ws + 1114112);    //  KS MB  split-K partials

    // adaptive mid-layer ksplit: 16 (2 blocks/CU) if workspace permits
    size_t need16 = (size_t)1114112 + (size_t)16 * 1048576;
    int KS = (ws_size >= need16) ? 16 : 8;
    int kchunk = 4096 / KS;

    // L1: fused build-X + GEMM + epilogue -> Ha   (K=256, full-K, nit=8)
    k_gemm<1, 1><<<dim3(32, 1), 256, 0, stream>>>(
        nullptr, emb, W1, b1, nullptr, Ha, nullptr, 4096, 256);

    // L2: split-K -> Cp; reduce -> Hb
    k_gemm<0, 0><<<dim3(32, KS), 256, 0, stream>>>(
        Ha, nullptr, W2, nullptr, Cp, nullptr, nullptr, 4096, kchunk);
    k_reduce<<<1024, 256, 0, stream>>>(Cp, b2, Hb, nullptr, 4096, KS, 0);

    // L3: split-K -> Cp; reduce -> Ha
    k_gemm<0, 0><<<dim3(32, KS), 256, 0, stream>>>(
        Hb, nullptr, W3, nullptr, Cp, nullptr, nullptr, 4096, kchunk);
    k_reduce<<<1024, 256, 0, stream>>>(Cp, b3, Ha, nullptr, 4096, KS, 0);

    // L4: N=256, split-K KS=32 (kchunk=128, nit=4) -> Cp; reduce+sigmoid -> pol
    k_gemm<0, 0><<<dim3(2, 32), 256, 0, stream>>>(
        Ha, nullptr, W4, nullptr, Cp, nullptr, nullptr, 256, 128);
    k_reduce<<<64, 256, 0, stream>>>(Cp, b4, nullptr, pol, 256, 32, 1);

    // Power iteration + factored output
    k_power_out<<<1, 1024, 0, stream>>>(pol, Ts, outp);

    (void)in_sizes; (void)n_in; (void)out_size; (void)ws_size;
}